// Round 1
// 11998.353 us; speedup vs baseline: 2.1519x; 2.1519x over previous
//
#include <hip/hip_runtime.h>
#include <math.h>

#define B   64
#define T   64
#define TS  63
#define V   32000
#define E   512
#define H   1024
#define EH  2048
#define KC  64

__device__ __forceinline__ float sigmoidf_(float x) {
    return 1.0f / (1.0f + expf(-x));
}

// initial_state (B, EH) -> sT (EH, B)
__global__ __launch_bounds__(256) void transpose_init_kernel(
    const float* __restrict__ s, float* __restrict__ sT) {
    int idx = blockIdx.x * 256 + threadIdx.x;   // idx over EH*B
    int b = idx & (B - 1);
    int k = idx >> 6;
    sT[idx] = s[b * EH + k];
}

// h0[j][b] = sum_k sT[k][b] * encW[j][k], written to 4 state buffers.
// grid 64 blocks * 16 rows; thread = 1 row x 4 b. LDS-tiled, dbuf, reg-prefetch.
__global__ __launch_bounds__(256) void encoder2_kernel(
    const float* __restrict__ sT, const float* __restrict__ encW,
    float* __restrict__ h0_init, float* __restrict__ h1_init,
    float* __restrict__ c0T, float* __restrict__ c1T) {
    __shared__ __align__(16) float hs[2][KC][B];   // 32 KB
    __shared__ float ws[2][16][KC + 1];            // 8.1 KB (stride 65: conflict-free)
    const int tid = threadIdx.x;
    const int r   = tid >> 4;      // 0..15
    const int bg  = tid & 15;
    const int b0  = bg * 4;
    const int row = blockIdx.x * 16 + r;
    float a0 = 0.f, a1 = 0.f, a2 = 0.f, a3 = 0.f;
    const int S = EH / KC;   // 32 slices

    {   // stage slice 0
        const float4* g4 = (const float4*)sT;
        float4* hdst = (float4*)&hs[0][0][0];
        #pragma unroll
        for (int i = 0; i < 4; ++i) hdst[tid + i * 256] = g4[tid + i * 256];
        float4 wv = *(const float4*)&encW[(size_t)row * EH + b0];
        ws[0][r][b0 + 0] = wv.x; ws[0][r][b0 + 1] = wv.y;
        ws[0][r][b0 + 2] = wv.z; ws[0][r][b0 + 3] = wv.w;
    }
    __syncthreads();

    for (int s = 0; s < S; ++s) {
        const int buf = s & 1;
        float4 hp[4]; float4 wp;
        const bool pf = (s + 1 < S);
        if (pf) {   // issue next-slice global loads BEFORE compute (hide latency)
            const int k0 = (s + 1) * KC;
            const float4* g4 = (const float4*)(sT + (size_t)k0 * B);
            #pragma unroll
            for (int i = 0; i < 4; ++i) hp[i] = g4[tid + i * 256];
            wp = *(const float4*)&encW[(size_t)row * EH + k0 + b0];
        }
        const float* hptr = &hs[buf][0][b0];
        const float* wptr = &ws[buf][r][0];
        #pragma unroll
        for (int kk = 0; kk < KC; ++kk) {
            float4 hv = *(const float4*)(hptr + kk * B);
            float wv = wptr[kk];
            a0 = fmaf(wv, hv.x, a0);
            a1 = fmaf(wv, hv.y, a1);
            a2 = fmaf(wv, hv.z, a2);
            a3 = fmaf(wv, hv.w, a3);
        }
        if (pf) {
            const int nb = buf ^ 1;
            float4* hdst = (float4*)&hs[nb][0][0];
            #pragma unroll
            for (int i = 0; i < 4; ++i) hdst[tid + i * 256] = hp[i];
            ws[nb][r][b0 + 0] = wp.x; ws[nb][r][b0 + 1] = wp.y;
            ws[nb][r][b0 + 2] = wp.z; ws[nb][r][b0 + 3] = wp.w;
        }
        __syncthreads();
    }
    float4 v = make_float4(a0, a1, a2, a3);
    int off = row * B + b0;
    *(float4*)&h0_init[off] = v;
    *(float4*)&h1_init[off] = v;
    *(float4*)&c0T[off] = v;
    *(float4*)&c1T[off] = v;
}

// xT_all[t][k][b] = emb[ids[b][t]][k]   (t in [0,63))
__global__ __launch_bounds__(256) void gather_kernel(
    const int* __restrict__ ids, const float* __restrict__ emb,
    float* __restrict__ xT_all) {
    int idx = blockIdx.x * 256 + threadIdx.x;   // over TS*E*B
    int b = idx & (B - 1);
    int r = idx >> 6;
    int k = r & (E - 1);
    int t = r >> 9;                              // E = 512 = 2^9
    int row = ids[b * T + t];
    xT_all[idx] = emb[(size_t)row * E + k];
}

// Fused LSTM cell, LDS-tiled GEMM.
// grid 256 blocks; block owns jj0..jj0+3 (x 4 gates = 16 rows) x 64 batch.
// thread: r = tid>>4 (row: gate=r>>2, jl=r&3), bg = tid&15 -> 4 consecutive b.
// Two phases: (xA, WA, nsA*KC cols, row stride ldA) then (xB, WB, H cols).
// Slice s+1 prefetched into registers before compute of slice s (dbuf LDS).
__global__ __launch_bounds__(256) void lstm_cell2_kernel(
    const float* __restrict__ xA, const float* __restrict__ WA, int nsA, int ldA,
    const float* __restrict__ xB, const float* __restrict__ WB,
    const float* __restrict__ b_ih, const float* __restrict__ b_hh,
    float* __restrict__ cT, float* __restrict__ hT_out) {
    __shared__ __align__(16) float hs[2][KC][B];   // 32 KB
    __shared__ float ws[2][16][KC + 1];            // 8.1 KB
    __shared__ __align__(16) float gsh[16][B];     // 4 KB gates exchange
    const int tid = threadIdx.x;
    const int r   = tid >> 4;                 // 0..15
    const int bg  = tid & 15;
    const int b0  = bg * 4;
    const int jj0 = blockIdx.x * 4;
    const int row = (r >> 2) * H + jj0 + (r & 3);   // gate*H + hidden unit
    const int S = nsA + H / KC;

    float bias = b_ih[row] + b_hh[row];
    float a0 = bias, a1 = bias, a2 = bias, a3 = bias;

    {   // stage slice 0 (phase A, k0 = 0)
        const float4* g4 = (const float4*)xA;
        float4* hdst = (float4*)&hs[0][0][0];
        #pragma unroll
        for (int i = 0; i < 4; ++i) hdst[tid + i * 256] = g4[tid + i * 256];
        float4 wv = *(const float4*)&WA[(size_t)row * ldA + b0];
        ws[0][r][b0 + 0] = wv.x; ws[0][r][b0 + 1] = wv.y;
        ws[0][r][b0 + 2] = wv.z; ws[0][r][b0 + 3] = wv.w;
    }
    __syncthreads();

    for (int s = 0; s < S; ++s) {
        const int buf = s & 1;
        float4 hp[4]; float4 wp;
        const bool pf = (s + 1 < S);
        if (pf) {   // issue next-slice global loads BEFORE compute
            const int sn = s + 1;
            const float* xs; const float* wsrc; int ld, k0;
            if (sn < nsA) { xs = xA; wsrc = WA; ld = ldA; k0 = sn * KC; }
            else { int sb = sn - nsA; xs = xB; wsrc = WB; ld = H; k0 = sb * KC; }
            const float4* g4 = (const float4*)(xs + (size_t)k0 * B);
            #pragma unroll
            for (int i = 0; i < 4; ++i) hp[i] = g4[tid + i * 256];
            wp = *(const float4*)&wsrc[(size_t)row * ld + k0 + b0];
        }
        const float* hptr = &hs[buf][0][b0];
        const float* wptr = &ws[buf][r][0];
        #pragma unroll
        for (int kk = 0; kk < KC; ++kk) {
            float4 hv = *(const float4*)(hptr + kk * B);
            float wv = wptr[kk];
            a0 = fmaf(wv, hv.x, a0);
            a1 = fmaf(wv, hv.y, a1);
            a2 = fmaf(wv, hv.z, a2);
            a3 = fmaf(wv, hv.w, a3);
        }
        if (pf) {
            const int nb = buf ^ 1;
            float4* hdst = (float4*)&hs[nb][0][0];
            #pragma unroll
            for (int i = 0; i < 4; ++i) hdst[tid + i * 256] = hp[i];
            ws[nb][r][b0 + 0] = wp.x; ws[nb][r][b0 + 1] = wp.y;
            ws[nb][r][b0 + 2] = wp.z; ws[nb][r][b0 + 3] = wp.w;
        }
        __syncthreads();
    }

    // exchange gates (i,f,g,o live in different waves), then fused elementwise
    *(float4*)&gsh[r][b0] = make_float4(a0, a1, a2, a3);
    __syncthreads();

    const int jl2 = tid >> 6;   // 0..3 local hidden unit
    const int bb  = tid & 63;
    float gi = gsh[0  + jl2][bb];
    float gf = gsh[4  + jl2][bb];
    float gg = gsh[8  + jl2][bb];
    float go = gsh[12 + jl2][bb];
    int off = (jj0 + jl2) * B + bb;
    float ig = sigmoidf_(gi);
    float fg = sigmoidf_(gf);
    float g2 = tanhf(gg);
    float og = sigmoidf_(go);
    float cn = fg * cT[off] + ig * g2;
    cT[off] = cn;
    hT_out[off] = og * tanhf(cn);
}

// Batched logits GEMM: out[b][t][v] = sum_k h1_all[t][k][b] * proj_W[v][k] + proj_b[v]
// grid (t fastest, v-tile second) so consecutive blocks share the proj_W slice
// -> proj_W streamed from HBM ~once instead of 63x. Bs stored k-major for
// vectorized conflict-free inner reads. Micro-tile 8v x 4b per thread.
#define VT 128
#define KC2 32
__global__ __launch_bounds__(256) void logits_gemm_kernel(
    const float* __restrict__ h1_all, const float* __restrict__ proj_W,
    const float* __restrict__ proj_b, float* __restrict__ out) {
    __shared__ __align__(16) float As[KC2][B];        // 8 KB
    __shared__ __align__(16) float Bs[KC2][VT + 2];   // 16.6 KB, stride 130
    const int t  = blockIdx.x;
    const int v0 = blockIdx.y * VT;
    const int tid = threadIdx.x;
    const int tx = tid & 15;    // b group: b = tx*4 + ib
    const int ty = tid >> 4;    // v group: v = ty*8 + iv

    float acc[8][4];
    #pragma unroll
    for (int iv = 0; iv < 8; ++iv)
        #pragma unroll
        for (int ib = 0; ib < 4; ++ib) acc[iv][ib] = 0.0f;

    const float* hbase = h1_all + (size_t)t * H * B;
    for (int k0 = 0; k0 < H; k0 += KC2) {
        const float4* asrc = (const float4*)(hbase + (size_t)k0 * B);
        #pragma unroll
        for (int i = 0; i < 2; ++i)
            ((float4*)As)[tid + i * 256] = asrc[tid + i * 256];
        #pragma unroll
        for (int i = 0; i < 4; ++i) {
            int f = tid + i * 256;            // 0..1023 float4s of the tile
            int vv = f >> 3;
            int kq = (f & 7) * 4;
            float4 w = *(const float4*)&proj_W[(size_t)(v0 + vv) * H + k0 + kq];
            Bs[kq + 0][vv] = w.x;
            Bs[kq + 1][vv] = w.y;
            Bs[kq + 2][vv] = w.z;
            Bs[kq + 3][vv] = w.w;
        }
        __syncthreads();
        #pragma unroll
        for (int kk = 0; kk < KC2; ++kk) {
            float4 a = *(const float4*)&As[kk][tx * 4];
            float2 b01 = *(const float2*)&Bs[kk][ty * 8 + 0];
            float2 b23 = *(const float2*)&Bs[kk][ty * 8 + 2];
            float2 b45 = *(const float2*)&Bs[kk][ty * 8 + 4];
            float2 b67 = *(const float2*)&Bs[kk][ty * 8 + 6];
            float bv[8] = {b01.x, b01.y, b23.x, b23.y, b45.x, b45.y, b67.x, b67.y};
            #pragma unroll
            for (int iv = 0; iv < 8; ++iv) {
                acc[iv][0] = fmaf(bv[iv], a.x, acc[iv][0]);
                acc[iv][1] = fmaf(bv[iv], a.y, acc[iv][1]);
                acc[iv][2] = fmaf(bv[iv], a.z, acc[iv][2]);
                acc[iv][3] = fmaf(bv[iv], a.w, acc[iv][3]);
            }
        }
        __syncthreads();
    }
    #pragma unroll
    for (int iv = 0; iv < 8; ++iv) {
        int v = v0 + ty * 8 + iv;
        float bias = proj_b[v];
        #pragma unroll
        for (int ib = 0; ib < 4; ++ib) {
            int b = tx * 4 + ib;
            out[((size_t)b * TS + t) * V + v] = acc[iv][ib] + bias;
        }
    }
}

// preds[b][t] = argmax_v logits[b][t][v]  (first index on ties)
__global__ __launch_bounds__(256) void argmax_kernel(
    const float* __restrict__ logits, float* __restrict__ preds) {
    int bt = blockIdx.x;
    const float* row = logits + (size_t)bt * V;
    float best = -1e30f;
    int bidx = 0;
    for (int v = threadIdx.x; v < V; v += 256) {
        float val = row[v];
        if (val > best) { best = val; bidx = v; }
    }
    __shared__ float sv[256];
    __shared__ int si[256];
    sv[threadIdx.x] = best;
    si[threadIdx.x] = bidx;
    __syncthreads();
    for (int s = 128; s > 0; s >>= 1) {
        if (threadIdx.x < s) {
            float o = sv[threadIdx.x + s];
            int oi = si[threadIdx.x + s];
            if (o > sv[threadIdx.x] ||
                (o == sv[threadIdx.x] && oi < si[threadIdx.x])) {
                sv[threadIdx.x] = o;
                si[threadIdx.x] = oi;
            }
        }
        __syncthreads();
    }
    if (threadIdx.x == 0) preds[bt] = (float)si[0];
}

extern "C" void kernel_launch(void* const* d_in, const int* in_sizes, int n_in,
                              void* d_out, int out_size, void* d_ws, size_t ws_size,
                              hipStream_t stream) {
    const int*   ids        = (const int*)d_in[0];
    const float* init_state = (const float*)d_in[1];
    const float* emb        = (const float*)d_in[2];
    const float* encW       = (const float*)d_in[3];
    const float* W_ih0      = (const float*)d_in[4];
    const float* W_hh0      = (const float*)d_in[5];
    const float* b_ih0      = (const float*)d_in[6];
    const float* b_hh0      = (const float*)d_in[7];
    const float* W_ih1      = (const float*)d_in[8];
    const float* W_hh1      = (const float*)d_in[9];
    const float* b_ih1      = (const float*)d_in[10];
    const float* b_hh1      = (const float*)d_in[11];
    const float* proj_W     = (const float*)d_in[12];
    const float* proj_b     = (const float*)d_in[13];

    float* out = (float*)d_out;
    float* preds = out;            // 64*63 floats
    float* logits = out + B * TS;  // 64*63*32000 floats

    float* ws = (float*)d_ws;
    float* sT      = ws;                        // EH*B
    float* h0_init = sT + EH * B;               // H*B
    float* h1_init = h0_init + H * B;           // H*B
    float* c0T     = h1_init + H * B;           // H*B
    float* c1T     = c0T + H * B;               // H*B
    float* xT_all  = c1T + H * B;               // TS*E*B
    float* h0_all  = xT_all + (size_t)TS * E * B;  // TS*H*B
    float* h1_all  = h0_all + (size_t)TS * H * B;  // TS*H*B

    transpose_init_kernel<<<(EH * B) / 256, 256, 0, stream>>>(init_state, sT);
    encoder2_kernel<<<H / 16, 256, 0, stream>>>(sT, encW, h0_init, h1_init, c0T, c1T);
    gather_kernel<<<(TS * E * B) / 256, 256, 0, stream>>>(ids, emb, xT_all);

    for (int t = 0; t < TS; ++t) {
        const float* x0   = xT_all + (size_t)t * E * B;
        const float* h0in = t ? h0_all + (size_t)(t - 1) * H * B : h0_init;
        float* h0out      = h0_all + (size_t)t * H * B;
        lstm_cell2_kernel<<<H / 4, 256, 0, stream>>>(
            x0, W_ih0, E / KC, E, h0in, W_hh0, b_ih0, b_hh0, c0T, h0out);

        const float* h1in = t ? h1_all + (size_t)(t - 1) * H * B : h1_init;
        float* h1out      = h1_all + (size_t)t * H * B;
        lstm_cell2_kernel<<<H / 4, 256, 0, stream>>>(
            h0out, W_ih1, H / KC, H, h1in, W_hh1, b_ih1, b_hh1, c1T, h1out);
    }

    logits_gemm_kernel<<<dim3(TS, V / VT), 256, 0, stream>>>(
        h1_all, proj_W, proj_b, logits);
    argmax_kernel<<<B * TS, 256, 0, stream>>>(logits, preds);
}